// Round 3
// baseline (283.054 us; speedup 1.0000x reference)
//
#include <hip/hip_runtime.h>
#include <hip/hip_bf16.h>
#include <math.h>

// out = (M + sum_{s=1..6} P_s)/sqrt(7), P_s = M*P_{s-1}/d_s, P_0 = M (powers
// of M commute, so M*P == P*M; M on the LEFT lets P ride as the MFMA B
// operand). One 256-thread block per 64x64 matrix; wave w owns COLUMN strip
// [16w,16w+16). A = M lives in registers (16 hi + 16 lo frags = 64 VGPR),
// constant over stages. Stage transition C-layout -> B-layout stays within
// the 4 lanes sharing (lane&15): done with 16 ds_bpermute + cndmask selects,
// NO LDS round trip, NO barriers after init. Split precision: x = hi+lo
// (bf16 pair), product = Ahi*Bhi + Ahi*Blo + Alo*Bhi (fp32 MFMA accum).

#define RDIM 64
#define MSTR 68   // fp32 row stride: keeps float4 alignment, spreads banks

using bf16x8 = __attribute__((ext_vector_type(8))) short;
using f32x4  = __attribute__((ext_vector_type(4))) float;

static __device__ __forceinline__ short f2bf(float x) {
    union { __hip_bfloat16 b; short s; } u; u.b = __float2bfloat16(x); return u.s;
}
static __device__ __forceinline__ float bf2f(short s) {
    union { short s2[2]; float f; } u; u.s2[0] = 0; u.s2[1] = s; return u.f;
}

__global__ __launch_bounds__(256, 3) void power_series_kernel(
        const float* __restrict__ M, float* __restrict__ out) {
    __shared__ float Ms[RDIM][MSTR];   // 17.4 KB; read-only after one barrier

    const int tid  = threadIdx.x;
    const int w    = tid >> 6;        // wave: column strip [16w, 16w+16)
    const int lane = tid & 63;
    const int q    = lane >> 4;       // quad 0..3
    const int l    = lane & 15;

    const float* Mg = M   + (size_t)blockIdx.x * (RDIM * RDIM);
    float*       Og = out + (size_t)blockIdx.x * (RDIM * RDIM);

    // ---- stage M into LDS (coalesced float4, balanced banks)
    {
        const float4* Mg4 = reinterpret_cast<const float4*>(Mg);
        #pragma unroll
        for (int v = 0; v < 4; ++v) {
            int e = tid + 256 * v;              // float4 index
            float4 x = Mg4[e];
            int row = (e * 4) >> 6, col = (e * 4) & 63;
            *reinterpret_cast<float4*>(&Ms[row][col]) = x;
        }
    }
    __syncthreads();   // the ONLY barrier

    // ---- A frags (constant): lane holds A[m=16t+l][k=32kb+8q+j], j=0..7
    bf16x8 amhi[4][2], amlo[4][2];
    #pragma unroll
    for (int t = 0; t < 4; ++t) {
        #pragma unroll
        for (int kb = 0; kb < 2; ++kb) {
            const float* src = &Ms[16 * t + l][32 * kb + 8 * q];   // 16B-aligned
            float4 x0 = *reinterpret_cast<const float4*>(src);
            float4 x1 = *reinterpret_cast<const float4*>(src + 4);
            float xs[8] = {x0.x, x0.y, x0.z, x0.w, x1.x, x1.y, x1.z, x1.w};
            bf16x8 hv, lv;
            #pragma unroll
            for (int j = 0; j < 8; ++j) {
                short h = f2bf(xs[j]); hv[j] = h;
                lv[j] = f2bf(xs[j] - bf2f(h));
            }
            amhi[t][kb] = hv; amlo[t][kb] = lv;
        }
    }

    // ---- B frags of P0 = M: lane holds B[k=32kb+8q+j][n=16w+l]
    bf16x8 pbhi[2], pblo[2];
    #pragma unroll
    for (int kb = 0; kb < 2; ++kb) {
        float xs[8];
        #pragma unroll
        for (int jj = 0; jj < 8; ++jj) {
            int j = (jj + 2 * q) & 7;           // stagger -> spread banks
            xs[j] = Ms[32 * kb + 8 * q + j][16 * w + l];
        }
        bf16x8 hv, lv;
        #pragma unroll
        for (int j = 0; j < 8; ++j) {
            short h = f2bf(xs[j]); hv[j] = h;
            lv[j] = f2bf(xs[j] - bf2f(h));
        }
        pbhi[kb] = hv; pblo[kb] = lv;
    }

    // ---- bpermute source addresses (byte addr = srclane*4)
    const int sA    = 2 * (q & 1) + (q >> 1);
    const int addrA = ((sA << 4) + l) << 2;
    const int addrB = ((((sA ^ 1)) << 4) + l) << 2;
    const int qlo   = q & 1;
    const int qhi   = q >> 1;

    // ---- decay constants (exact integer variances)
    const double V[7] = {1.0, 64.0, 4104.0, 263696.0, 17021060.0,
                         1104218816.0, 72260728960.0};
    float invd[7];
    invd[0] = 1.0f;
    #pragma unroll
    for (int i = 1; i < 7; ++i) invd[i] = (float)(1.0 / sqrt(V[i] / V[i - 1]));

    f32x4 acc[4];
    #pragma unroll
    for (int t = 0; t < 4; ++t) acc[t] = (f32x4){0.f, 0.f, 0.f, 0.f};

    #pragma unroll
    for (int s = 1; s <= 6; ++s) {
        f32x4 c[4];
        #pragma unroll
        for (int t = 0; t < 4; ++t) {
            f32x4 cc = (f32x4){0.f, 0.f, 0.f, 0.f};
            cc = __builtin_amdgcn_mfma_f32_16x16x32_bf16(amhi[t][0], pbhi[0], cc, 0, 0, 0);
            cc = __builtin_amdgcn_mfma_f32_16x16x32_bf16(amhi[t][1], pbhi[1], cc, 0, 0, 0);
            cc = __builtin_amdgcn_mfma_f32_16x16x32_bf16(amhi[t][0], pblo[0], cc, 0, 0, 0);
            cc = __builtin_amdgcn_mfma_f32_16x16x32_bf16(amhi[t][1], pblo[1], cc, 0, 0, 0);
            cc = __builtin_amdgcn_mfma_f32_16x16x32_bf16(amlo[t][0], pbhi[0], cc, 0, 0, 0);
            cc = __builtin_amdgcn_mfma_f32_16x16x32_bf16(amlo[t][1], pbhi[1], cc, 0, 0, 0);
            c[t] = cc;
        }
        const float inv = invd[s];

        if (s < 6) {
            // pack P_s (scaled) into paired-bf16 dwords: pd[t][h] = rows
            // 16t+4q+2h,+1 of column 16w+l (low half = even row)
            int pdh[4][2], pdl[4][2];
            #pragma unroll
            for (int t = 0; t < 4; ++t) {
                #pragma unroll
                for (int h = 0; h < 2; ++h) {
                    float a0 = c[t][2 * h] * inv, a1 = c[t][2 * h + 1] * inv;
                    acc[t][2 * h] += a0; acc[t][2 * h + 1] += a1;
                    short h0 = f2bf(a0), h1 = f2bf(a1);
                    pdh[t][h] = (h0 & 0xffff) | ((int)h1 << 16);
                    short g0 = f2bf(a0 - bf2f(h0)), g1 = f2bf(a1 - bf2f(h1));
                    pdl[t][h] = (g0 & 0xffff) | ((int)g1 << 16);
                }
            }
            // C-layout -> B-layout within l-groups: dest (q,l) dword d of
            // pb[kb] = rows 32kb+8q+2d,+1. Source quad holding it: tile
            // t_s=2kb+(q>>1) (fixed per dest), quads 2(q&1)+{0,1}.
            union { int d[4]; bf16x8 v; } nh[2], nl[2];
            #pragma unroll
            for (int kb = 0; kb < 2; ++kb) {
                #pragma unroll
                for (int h = 0; h < 2; ++h) {
                    int zA = qlo ? pdh[2 * kb + 1][h] : pdh[2 * kb][h];
                    int zB = qlo ? pdh[2 * kb][h]     : pdh[2 * kb + 1][h];
                    int rA = __builtin_amdgcn_ds_bpermute(addrA, zA);
                    int rB = __builtin_amdgcn_ds_bpermute(addrB, zB);
                    nh[kb].d[h]     = qhi ? rB : rA;   // d = h     (rows +2h)
                    nh[kb].d[2 + h] = qhi ? rA : rB;   // d = 2+h   (rows +4+2h)
                    zA = qlo ? pdl[2 * kb + 1][h] : pdl[2 * kb][h];
                    zB = qlo ? pdl[2 * kb][h]     : pdl[2 * kb + 1][h];
                    rA = __builtin_amdgcn_ds_bpermute(addrA, zA);
                    rB = __builtin_amdgcn_ds_bpermute(addrB, zB);
                    nl[kb].d[h]     = qhi ? rB : rA;
                    nl[kb].d[2 + h] = qhi ? rA : rB;
                }
            }
            pbhi[0] = nh[0].v; pbhi[1] = nh[1].v;
            pblo[0] = nl[0].v; pblo[1] = nl[1].v;
        } else {
            #pragma unroll
            for (int t = 0; t < 4; ++t)
                #pragma unroll
                for (int r = 0; r < 4; ++r)
                    acc[t][r] += c[t][r] * inv;
        }
    }

    // ---- epilogue: out = (M + acc)/sqrt(7); M re-read from LDS (still valid)
    const float oscale = 0.3779644730092272f;   // 1/sqrt(7)
    #pragma unroll
    for (int t = 0; t < 4; ++t) {
        #pragma unroll
        for (int r = 0; r < 4; ++r) {
            int row = 16 * t + 4 * q + r;
            int col = 16 * w + l;
            Og[row * 64 + col] = (acc[t][r] + Ms[row][col]) * oscale;
        }
    }
}

extern "C" void kernel_launch(void* const* d_in, const int* in_sizes, int n_in,
                              void* d_out, int out_size, void* d_ws, size_t ws_size,
                              hipStream_t stream) {
    const float* M = (const float*)d_in[0];
    float* out = (float*)d_out;
    const int nmat = in_sizes[0] / (RDIM * RDIM);   // 8192
    power_series_kernel<<<dim3(nmat), dim3(256), 0, stream>>>(M, out);
}